// Round 1
// baseline (21.697 us; speedup 1.0000x reference)
//
#include <hip/hip_runtime.h>
#include <math.h>

// Problem constants
#define WIRES 4
#define DIM 16          // 2^WIRES
#define OUT_C 16
#define QDEPTH 2
#define H 128
#define W 128
#define B 16

// ---------------------------------------------------------------------------
// Kernel 1: build the 16x16 circuit unitary U from weights[2][4][3].
// Thread t (t<16) evolves basis state |t> through the circuit; the resulting
// state vector is column t of U. Store Ur (ws[0..255]) and Ui (ws[256..511]),
// layout U{r,i}[row*16 + col].
// ---------------------------------------------------------------------------
__global__ void build_unitary(const float* __restrict__ w, float* __restrict__ ws) {
    int col = threadIdx.x;
    if (col >= DIM) return;

    float sr[DIM], si[DIM];
#pragma unroll
    for (int i = 0; i < DIM; ++i) { sr[i] = 0.f; si[i] = 0.f; }
    sr[col] = 1.f;

#pragma unroll
    for (int l = 0; l < QDEPTH; ++l) {
        // Rot on every wire: U = [[ep*c, -conj(em)*s],[em*s, conj(ep)*c]]
        // ep = exp(-0.5i(phi+omega)), em = exp(-0.5i(phi-omega))
#pragma unroll
        for (int q = 0; q < WIRES; ++q) {
            float phi   = w[(l * WIRES + q) * 3 + 0];
            float theta = w[(l * WIRES + q) * 3 + 1];
            float omega = w[(l * WIRES + q) * 3 + 2];
            float c = cosf(0.5f * theta);
            float s = sinf(0.5f * theta);
            float ap = 0.5f * (phi + omega);
            float am = 0.5f * (phi - omega);
            float epr = cosf(ap), epi = -sinf(ap);   // ep = epr + i*epi
            float emr = cosf(am), emi = -sinf(am);   // em = emr + i*emi
            // U00 = ep*c
            float u00r = epr * c, u00i = epi * c;
            // U01 = -conj(em)*s = (-emr + i*emi)*s
            float u01r = -emr * s, u01i = emi * s;
            // U10 = em*s
            float u10r = emr * s, u10i = emi * s;
            // U11 = conj(ep)*c = (epr - i*epi)*c
            float u11r = epr * c, u11i = -epi * c;

            const int m = 8 >> q;   // wire 0 = MSB of the 4-bit index
#pragma unroll
            for (int i0 = 0; i0 < DIM; ++i0) {
                if (i0 & m) continue;
                int i1 = i0 | m;
                float ar = sr[i0], ai = si[i0];
                float br = sr[i1], bi = si[i1];
                sr[i0] = u00r * ar - u00i * ai + u01r * br - u01i * bi;
                si[i0] = u00r * ai + u00i * ar + u01r * bi + u01i * br;
                sr[i1] = u10r * ar - u10i * ai + u11r * br - u11i * bi;
                si[i1] = u10r * ai + u10i * ar + u11r * bi + u11i * br;
            }
        }
        // Ring of CNOTs, range r = l % (WIRES-1) + 1, control i -> target (i+r)%WIRES
        const int r = (l % (WIRES - 1)) + 1;
#pragma unroll
        for (int i = 0; i < WIRES; ++i) {
            const int mc = 8 >> i;
            const int mt = 8 >> ((i + r) & (WIRES - 1));
#pragma unroll
            for (int i0 = 0; i0 < DIM; ++i0) {
                if (!(i0 & mc)) continue;   // control must be 1
                if (i0 & mt) continue;      // take target=0 member of the pair
                int i1 = i0 | mt;
                float tr = sr[i0], ti = si[i0];
                sr[i0] = sr[i1]; si[i0] = si[i1];
                sr[i1] = tr;     si[i1] = ti;
            }
        }
    }

#pragma unroll
    for (int row = 0; row < DIM; ++row) {
        ws[row * DIM + col]       = sr[row];
        ws[256 + row * DIM + col] = si[row];
    }
}

// ---------------------------------------------------------------------------
// Kernel 2: per-pixel evaluation.
// out[b][k][y][x] = min(8 * ((Ur[k]·p)^2 + (Ui[k]·p)^2) / ||p||^2, 1)
// p[0..8] = 3x3 zero-padded patch + 0.01, p[9..15] = 0.01
// ---------------------------------------------------------------------------
__global__ __launch_bounds__(256) void qconv_eval(const float* __restrict__ x,
                                                  const float* __restrict__ ws,
                                                  float* __restrict__ out) {
    __shared__ float U[512];
    for (int i = threadIdx.x; i < 512; i += 256) U[i] = ws[i];
    __syncthreads();

    int gid = blockIdx.x * 256 + threadIdx.x;
    if (gid >= B * H * W) return;
    int xc = gid & (W - 1);
    int yc = (gid >> 7) & (H - 1);
    int b  = gid >> 14;

    const float* img = x + b * (H * W);

    float p[DIM];
#pragma unroll
    for (int i = 0; i < 3; ++i) {
#pragma unroll
        for (int j = 0; j < 3; ++j) {
            int yy = yc + i - 1;
            int xx = xc + j - 1;
            float v = (yy >= 0 && yy < H && xx >= 0 && xx < W) ? img[yy * W + xx] : 0.f;
            p[i * 3 + j] = v + 0.01f;
        }
    }
#pragma unroll
    for (int j = 9; j < DIM; ++j) p[j] = 0.01f;

    float n2 = 0.f;
#pragma unroll
    for (int j = 0; j < DIM; ++j) n2 += p[j] * p[j];
    float scale = 8.0f / n2;   // (DIM*0.5) / norm^2

    float* o = out + ((size_t)b * OUT_C) * (H * W) + yc * W + xc;
#pragma unroll
    for (int k = 0; k < OUT_C; ++k) {
        float u = 0.f, v = 0.f;
#pragma unroll
        for (int j = 0; j < DIM; ++j) {
            float pj = p[j];
            u += U[k * DIM + j] * pj;
            v += U[256 + k * DIM + j] * pj;
        }
        float val = (u * u + v * v) * scale;
        o[(size_t)k * (H * W)] = fminf(val, 1.0f);
    }
}

extern "C" void kernel_launch(void* const* d_in, const int* in_sizes, int n_in,
                              void* d_out, int out_size, void* d_ws, size_t ws_size,
                              hipStream_t stream) {
    const float* x = (const float*)d_in[0];        // [16,1,128,128] f32
    const float* w = (const float*)d_in[1];        // [2,4,3] f32
    float* out = (float*)d_out;                    // [16,16,128,128] f32
    float* ws  = (float*)d_ws;

    build_unitary<<<1, 64, 0, stream>>>(w, ws);

    int npix = B * H * W;                          // 262144
    qconv_eval<<<npix / 256, 256, 0, stream>>>(x, ws, out);
}

// Round 2
// 21.657 us; speedup vs baseline: 1.0018x; 1.0018x over previous
//
#include <hip/hip_runtime.h>
#include <math.h>

// Problem constants
#define WIRES 4
#define DIM 16          // 2^WIRES
#define OUT_C 16
#define QDEPTH 2
#define H 128
#define W 128
#define B 16

typedef __attribute__((ext_vector_type(8))) float f32x8;
typedef __attribute__((ext_vector_type(2))) float f32x2;

// ---------------------------------------------------------------------------
// Kernel 1: build the 16x16 circuit unitary U from weights[2][4][3], then
// store per-output-row records into ws:
//   record k (32 floats, 128 B):
//     [0..8]  = Ur[k][0..8]
//     [9]     = dR[k] = 0.01 * sum_{j=9..15} Ur[k][j]
//     [16..24]= Ui[k][0..8]
//     [25]    = dI[k] = 0.01 * sum_{j=9..15} Ui[k][j]
// Thread t (t<16) evolves basis state |t> -> column t of U. Rows are gathered
// through LDS (transpose) to form the records.
// ---------------------------------------------------------------------------
__global__ void build_unitary(const float* __restrict__ w, float* __restrict__ ws) {
    __shared__ float Utr[DIM][DIM];
    __shared__ float Uti[DIM][DIM];

    int tid = threadIdx.x;
    int col = tid & (DIM - 1);

    float sr[DIM], si[DIM];
#pragma unroll
    for (int i = 0; i < DIM; ++i) { sr[i] = 0.f; si[i] = 0.f; }
    sr[col] = 1.f;

#pragma unroll
    for (int l = 0; l < QDEPTH; ++l) {
        // Rot on every wire: U = [[ep*c, -conj(em)*s],[em*s, conj(ep)*c]]
#pragma unroll
        for (int q = 0; q < WIRES; ++q) {
            float phi   = w[(l * WIRES + q) * 3 + 0];
            float theta = w[(l * WIRES + q) * 3 + 1];
            float omega = w[(l * WIRES + q) * 3 + 2];
            float c = cosf(0.5f * theta);
            float s = sinf(0.5f * theta);
            float ap = 0.5f * (phi + omega);
            float am = 0.5f * (phi - omega);
            float epr = cosf(ap), epi = -sinf(ap);
            float emr = cosf(am), emi = -sinf(am);
            float u00r = epr * c, u00i = epi * c;
            float u01r = -emr * s, u01i = emi * s;
            float u10r = emr * s, u10i = emi * s;
            float u11r = epr * c, u11i = -epi * c;

            const int m = 8 >> q;
#pragma unroll
            for (int i0 = 0; i0 < DIM; ++i0) {
                if (i0 & m) continue;
                int i1 = i0 | m;
                float ar = sr[i0], ai = si[i0];
                float br = sr[i1], bi = si[i1];
                sr[i0] = u00r * ar - u00i * ai + u01r * br - u01i * bi;
                si[i0] = u00r * ai + u00i * ar + u01r * bi + u01i * br;
                sr[i1] = u10r * ar - u10i * ai + u11r * br - u11i * bi;
                si[i1] = u10r * ai + u10i * ar + u11r * bi + u11i * br;
            }
        }
        const int r = (l % (WIRES - 1)) + 1;
#pragma unroll
        for (int i = 0; i < WIRES; ++i) {
            const int mc = 8 >> i;
            const int mt = 8 >> ((i + r) & (WIRES - 1));
#pragma unroll
            for (int i0 = 0; i0 < DIM; ++i0) {
                if (!(i0 & mc)) continue;
                if (i0 & mt) continue;
                int i1 = i0 | mt;
                float tr = sr[i0], ti = si[i0];
                sr[i0] = sr[i1]; si[i0] = si[i1];
                sr[i1] = tr;     si[i1] = ti;
            }
        }
    }

    if (tid < DIM) {
#pragma unroll
        for (int row = 0; row < DIM; ++row) {
            Utr[row][tid] = sr[row];
            Uti[row][tid] = si[row];
        }
    }
    __syncthreads();

    if (tid < DIM) {
        int k = tid;
        float accR = 0.f, accI = 0.f;
#pragma unroll
        for (int j = 0; j < 9; ++j) {
            ws[k * 32 + j]      = Utr[k][j];
            ws[k * 32 + 16 + j] = Uti[k][j];
        }
#pragma unroll
        for (int j = 9; j < DIM; ++j) {
            accR += Utr[k][j];
            accI += Uti[k][j];
        }
        ws[k * 32 + 9]  = 0.01f * accR;
        ws[k * 32 + 25] = 0.01f * accI;
    }
}

// ---------------------------------------------------------------------------
// Kernel 2: per-pixel evaluation. U records fetched via scalar loads (s_load)
// into SGPRs -> FMAs use the free SGPR operand slot; zero LDS traffic.
// ---------------------------------------------------------------------------
__global__ __launch_bounds__(256) void qconv_eval(const float* __restrict__ x,
                                                  const float* __restrict__ U,
                                                  float* __restrict__ out) {
    int gid = blockIdx.x * 256 + threadIdx.x;   // grid exactly covers B*H*W
    int xc = gid & (W - 1);
    int yc = (gid >> 7) & (H - 1);
    int b  = gid >> 14;

    const float* img = x + b * (H * W);

    // Branchless 3x3 patch (clamped address + select), +0.01 shift.
    float p[9];
#pragma unroll
    for (int i = 0; i < 3; ++i) {
#pragma unroll
        for (int j = 0; j < 3; ++j) {
            int yy = yc + i - 1;
            int xx = xc + j - 1;
            int yyc = min(max(yy, 0), H - 1);
            int xxc = min(max(xx, 0), W - 1);
            float v = img[yyc * W + xxc];
            bool inb = (yy == yyc) & (xx == xxc);
            p[i * 3 + j] = (inb ? v : 0.f) + 0.01f;
        }
    }

    float n2 = 7.0f * 1e-4f;   // tail: 7 entries of 0.01^2
#pragma unroll
    for (int j = 0; j < 9; ++j) n2 = fmaf(p[j], p[j], n2);
    float scale = 8.0f / n2;   // (DIM*0.5) / ||p||^2

    float* o = out + ((size_t)b * OUT_C) * (H * W) + yc * W + xc;

#pragma unroll
    for (int k = 0; k < OUT_C; ++k) {
        f32x8 ra, ia;
        f32x2 rb, ib;
        asm volatile(
            "s_load_dwordx8 %0, %4, %5\n\t"
            "s_load_dwordx2 %1, %4, %6\n\t"
            "s_load_dwordx8 %2, %4, %7\n\t"
            "s_load_dwordx2 %3, %4, %8\n\t"
            "s_waitcnt lgkmcnt(0)"
            : "=s"(ra), "=s"(rb), "=s"(ia), "=s"(ib)
            : "s"(U), "i"(k * 128), "i"(k * 128 + 32),
              "i"(k * 128 + 64), "i"(k * 128 + 96));

        float u = rb.y;   // dR[k]
        float v = ib.y;   // dI[k]
#pragma unroll
        for (int j = 0; j < 8; ++j) u = fmaf(ra[j], p[j], u);
        u = fmaf(rb.x, p[8], u);
#pragma unroll
        for (int j = 0; j < 8; ++j) v = fmaf(ia[j], p[j], v);
        v = fmaf(ib.x, p[8], v);

        float val = fmaf(u, u, v * v) * scale;
        o[(size_t)k * (H * W)] = fminf(val, 1.0f);
    }
}

extern "C" void kernel_launch(void* const* d_in, const int* in_sizes, int n_in,
                              void* d_out, int out_size, void* d_ws, size_t ws_size,
                              hipStream_t stream) {
    const float* x = (const float*)d_in[0];        // [16,1,128,128] f32
    const float* w = (const float*)d_in[1];        // [2,4,3] f32
    float* out = (float*)d_out;                    // [16,16,128,128] f32
    float* ws  = (float*)d_ws;                     // 512 floats used

    build_unitary<<<1, 64, 0, stream>>>(w, ws);

    int npix = B * H * W;                          // 262144 = 1024 * 256
    qconv_eval<<<npix / 256, 256, 0, stream>>>(x, ws, out);
}

// Round 3
// 20.882 us; speedup vs baseline: 1.0390x; 1.0371x over previous
//
#include <hip/hip_runtime.h>
#include <math.h>

#define WIRES 4
#define DIM 16
#define OUT_C 16
#define QDEPTH 2
#define H 128
#define W 128
#define B 16

typedef __attribute__((ext_vector_type(8))) float f32x8;
typedef __attribute__((ext_vector_type(4))) float f32x4;
typedef __attribute__((ext_vector_type(2))) float f32x2;

// ---------------------------------------------------------------------------
// Kernel 1: build the 16x16 circuit unitary from weights[2][4][3].
// Trig is computed IN PARALLEL: lane L computes one of the 48 needed
// cos/sin values (gate g = L/6, element e = L%6), then the evolving lanes
// fetch gate coefficients via __shfl. Lane t<16 evolves basis state |t>
// (column t of U). Records per output row k (32 floats each) go to ws:
//   [0..8] Ur[k][0..8], [9] dR[k]=0.01*sum_{j>=9}Ur[k][j],
//   [16..24] Ui[k][0..8], [25] dI[k]=0.01*sum_{j>=9}Ui[k][j]
// ---------------------------------------------------------------------------
__global__ void build_unitary(const float* __restrict__ w, float* __restrict__ ws) {
    __shared__ float Utr[DIM][DIM];
    __shared__ float Uti[DIM][DIM];

    int tid = threadIdx.x;              // 64 threads = 1 wave

    // ---- parallel trig: e0=cos(th/2) e1=sin(th/2) e2=cos(ap) e3=sin(ap)
    //                     e4=cos(am) e5=sin(am), ap=(phi+omega)/2, am=(phi-omega)/2
    int g = tid / 6;
    int e = tid - 6 * g;
    int gg = g < 8 ? g : 7;             // lanes 48..63: clamp (unused values)
    float phi   = w[gg * 3 + 0];
    float theta = w[gg * 3 + 1];
    float omega = w[gg * 3 + 2];
    float ang = (e < 2) ? 0.5f * theta
              : ((e < 4) ? 0.5f * (phi + omega) : 0.5f * (phi - omega));
    float sn = __sinf(ang);
    float cs = __cosf(ang);
    float trig = (e & 1) ? sn : cs;

    // ---- evolve column (all lanes run; only lanes 0..15 write)
    int col = tid & (DIM - 1);
    float sr[DIM], si[DIM];
#pragma unroll
    for (int i = 0; i < DIM; ++i) { sr[i] = 0.f; si[i] = 0.f; }
    sr[col] = 1.f;

#pragma unroll
    for (int l = 0; l < QDEPTH; ++l) {
#pragma unroll
        for (int q = 0; q < WIRES; ++q) {
            int gb = (l * WIRES + q) * 6;
            float c  = __shfl(trig, gb + 0);
            float s  = __shfl(trig, gb + 1);
            float cp = __shfl(trig, gb + 2);
            float sp = __shfl(trig, gb + 3);
            float cm = __shfl(trig, gb + 4);
            float sm = __shfl(trig, gb + 5);
            // ep = cp - i*sp ; em = cm - i*sm  (round-1 verified signs)
            float u00r = cp * c,  u00i = -sp * c;
            float u01r = -cm * s, u01i = -sm * s;
            float u10r = cm * s,  u10i = -sm * s;
            float u11r = cp * c,  u11i = sp * c;

            const int m = 8 >> q;
#pragma unroll
            for (int i0 = 0; i0 < DIM; ++i0) {
                if (i0 & m) continue;
                int i1 = i0 | m;
                float ar = sr[i0], ai = si[i0];
                float br = sr[i1], bi = si[i1];
                sr[i0] = u00r * ar - u00i * ai + u01r * br - u01i * bi;
                si[i0] = u00r * ai + u00i * ar + u01r * bi + u01i * br;
                sr[i1] = u10r * ar - u10i * ai + u11r * br - u11i * bi;
                si[i1] = u10r * ai + u10i * ar + u11r * bi + u11i * br;
            }
        }
        const int r = (l % (WIRES - 1)) + 1;
#pragma unroll
        for (int i = 0; i < WIRES; ++i) {
            const int mc = 8 >> i;
            const int mt = 8 >> ((i + r) & (WIRES - 1));
#pragma unroll
            for (int i0 = 0; i0 < DIM; ++i0) {
                if (!(i0 & mc)) continue;
                if (i0 & mt) continue;
                int i1 = i0 | mt;
                float tr = sr[i0], ti = si[i0];
                sr[i0] = sr[i1]; si[i0] = si[i1];
                sr[i1] = tr;     si[i1] = ti;
            }
        }
    }

    if (tid < DIM) {
#pragma unroll
        for (int row = 0; row < DIM; ++row) {
            Utr[row][tid] = sr[row];
            Uti[row][tid] = si[row];
        }
    }
    __syncthreads();

    if (tid < DIM) {
        int k = tid;
        float accR = 0.f, accI = 0.f;
#pragma unroll
        for (int j = 0; j < 9; ++j) {
            ws[k * 32 + j]      = Utr[k][j];
            ws[k * 32 + 16 + j] = Uti[k][j];
        }
#pragma unroll
        for (int j = 9; j < DIM; ++j) {
            accR += Utr[k][j];
            accI += Uti[k][j];
        }
        ws[k * 32 + 9]  = 0.01f * accR;
        ws[k * 32 + 25] = 0.01f * accI;
    }
}

// ---------------------------------------------------------------------------
// Kernel 2: 4 pixels per thread (one row strip of 4), float4 stores.
// U records via s_load into SGPRs (free operand slot on v_fmac).
// ---------------------------------------------------------------------------
__global__ __launch_bounds__(256) void qconv_eval(const float* __restrict__ x,
                                                  const float* __restrict__ U,
                                                  float* __restrict__ out) {
    int gid = blockIdx.x * 256 + threadIdx.x;   // 65536 threads
    int xg = (gid & 31) << 2;                   // x0 in {0,4,...,124}
    int yc = (gid >> 5) & (H - 1);
    int b  = gid >> 12;

    const float* img = x + b * (H * W);

    // Row window x0-1 .. x0+4 for 3 rows, shifted +0.01, OOB -> 0.01
    float r[3][6];
#pragma unroll
    for (int dy = 0; dy < 3; ++dy) {
        int yy = yc + dy - 1;
        int yyc = min(max(yy, 0), H - 1);
        bool rowok = (yy == yyc);
#pragma unroll
        for (int m = 0; m < 6; ++m) {
            int xx = xg + m - 1;
            int xxc = min(max(xx, 0), W - 1);
            float v = img[yyc * W + xxc];
            bool ok = rowok & (xx == xxc);
            r[dy][m] = (ok ? v : 0.f) + 0.01f;
        }
    }

    float scale[4];
#pragma unroll
    for (int i = 0; i < 4; ++i) {
        float n2 = 7.0f * 1e-4f;    // 7 tail entries of 0.01^2
#pragma unroll
        for (int dy = 0; dy < 3; ++dy)
#pragma unroll
            for (int dj = 0; dj < 3; ++dj) {
                float pv = r[dy][i + dj];
                n2 = fmaf(pv, pv, n2);
            }
        scale[i] = 8.0f / n2;       // (DIM*0.5)/||p||^2
    }

    float* o = out + ((size_t)b * OUT_C) * (H * W) + yc * W + xg;

#pragma unroll
    for (int k = 0; k < OUT_C; ++k) {
        f32x8 ra, ia;
        f32x2 rb, ib;
        asm volatile(
            "s_load_dwordx8 %0, %4, %5\n\t"
            "s_load_dwordx2 %1, %4, %6\n\t"
            "s_load_dwordx8 %2, %4, %7\n\t"
            "s_load_dwordx2 %3, %4, %8\n\t"
            "s_waitcnt lgkmcnt(0)"
            : "=s"(ra), "=s"(rb), "=s"(ia), "=s"(ib)
            : "s"(U), "i"(k * 128), "i"(k * 128 + 32),
              "i"(k * 128 + 64), "i"(k * 128 + 96));

        f32x4 res;
#pragma unroll
        for (int i = 0; i < 4; ++i) {
            float u = rb.y;   // dR[k]
            float v = ib.y;   // dI[k]
#pragma unroll
            for (int j = 0; j < 9; ++j) {
                float cR = (j < 8) ? ra[j] : rb.x;
                float cI = (j < 8) ? ia[j] : ib.x;
                float pv = r[j / 3][i + (j % 3)];
                u = fmaf(cR, pv, u);
                v = fmaf(cI, pv, v);
            }
            float val = fmaf(u, u, v * v) * scale[i];
            res[i] = fminf(val, 1.0f);
        }
        *(f32x4*)(o + (size_t)k * (H * W)) = res;   // 16B-aligned (xg%4==0)
    }
}

extern "C" void kernel_launch(void* const* d_in, const int* in_sizes, int n_in,
                              void* d_out, int out_size, void* d_ws, size_t ws_size,
                              hipStream_t stream) {
    const float* x = (const float*)d_in[0];        // [16,1,128,128] f32
    const float* w = (const float*)d_in[1];        // [2,4,3] f32
    float* out = (float*)d_out;                    // [16,16,128,128] f32
    float* ws  = (float*)d_ws;                     // 512 floats used

    build_unitary<<<1, 64, 0, stream>>>(w, ws);

    int nthreads = (B * H * W) / 4;                // 65536
    qconv_eval<<<nthreads / 256, 256, 0, stream>>>(x, ws, out);
}

// Round 4
// 14.992 us; speedup vs baseline: 1.4472x; 1.3929x over previous
//
#include <hip/hip_runtime.h>
#include <math.h>

#define WIRES 4
#define DIM 16
#define OUT_C 16
#define QDEPTH 2
#define H 128
#define W 128
#define B 16

typedef __attribute__((ext_vector_type(4))) float f32x4;

// ---------------------------------------------------------------------------
// Single fused kernel. Each block:
//   1) issues its 3x6 patch loads (latency hides under step 2),
//   2) wave 0 rebuilds the 16x16 circuit unitary (parallel trig across lanes,
//      16-lane column evolution — verbatim round-2 verified code) and stages
//      per-row records in LDS:
//        rec k (32 floats): [0..8]=Ur[k][0..8], [9]=dR[k]=0.01*sum_{j>=9}Ur[k][j]
//                           [16..24]=Ui[k][0..8], [25]=dI[k]=0.01*sum Ui
//   3) all threads evaluate 4 pixels x 16 channels, float4 stores.
// out[b][k][y][x] = min(8*((Ur[k].p)^2+(Ui[k].p)^2)/||p||^2, 1)
// ---------------------------------------------------------------------------
__global__ __launch_bounds__(256) void qconv_fused(const float* __restrict__ x,
                                                   const float* __restrict__ w,
                                                   float* __restrict__ out) {
    __shared__ float Utr[DIM][DIM];
    __shared__ float Uti[DIM][DIM];
    __shared__ float recs[512];

    const int tid = threadIdx.x;
    const int gid = blockIdx.x * 256 + tid;     // 65536 threads, 4 px each
    const int xg = (gid & 31) << 2;             // x0 in {0,4,...,124}
    const int yc = (gid >> 5) & (H - 1);
    const int b  = gid >> 12;

    const float* img = x + b * (H * W);

    // ---- 1) patch row window x0-1..x0+4 for 3 rows, +0.01, OOB -> 0.01 ----
    float r[3][6];
#pragma unroll
    for (int dy = 0; dy < 3; ++dy) {
        int yy = yc + dy - 1;
        int yyc = min(max(yy, 0), H - 1);
        bool rowok = (yy == yyc);
#pragma unroll
        for (int m = 0; m < 6; ++m) {
            int xx = xg + m - 1;
            int xxc = min(max(xx, 0), W - 1);
            float v = img[yyc * W + xxc];
            bool ok = rowok & (xx == xxc);
            r[dy][m] = (ok ? v : 0.f) + 0.01f;
        }
    }

    // ---- 2) wave 0: build U ----
    if (tid < 64) {
        // parallel trig: lane L -> gate g=L/6, element e=L%6
        // e: 0=cos(th/2) 1=sin(th/2) 2=cos(ap) 3=sin(ap) 4=cos(am) 5=sin(am)
        int g = tid / 6;
        int e = tid - 6 * g;
        int gg = g < 8 ? g : 7;
        float phi   = w[gg * 3 + 0];
        float theta = w[gg * 3 + 1];
        float omega = w[gg * 3 + 2];
        float ang = (e < 2) ? 0.5f * theta
                  : ((e < 4) ? 0.5f * (phi + omega) : 0.5f * (phi - omega));
        float sn = __sinf(ang);
        float cs = __cosf(ang);
        float trig = (e & 1) ? sn : cs;

        int col = tid & (DIM - 1);
        float sr[DIM], si[DIM];
#pragma unroll
        for (int i = 0; i < DIM; ++i) { sr[i] = 0.f; si[i] = 0.f; }
        sr[col] = 1.f;

#pragma unroll
        for (int l = 0; l < QDEPTH; ++l) {
#pragma unroll
            for (int q = 0; q < WIRES; ++q) {
                int gb = (l * WIRES + q) * 6;
                float c  = __shfl(trig, gb + 0);
                float s  = __shfl(trig, gb + 1);
                float cp = __shfl(trig, gb + 2);
                float sp = __shfl(trig, gb + 3);
                float cm = __shfl(trig, gb + 4);
                float sm = __shfl(trig, gb + 5);
                // ep = cp - i*sp ; em = cm - i*sm
                float u00r = cp * c,  u00i = -sp * c;
                float u01r = -cm * s, u01i = -sm * s;
                float u10r = cm * s,  u10i = -sm * s;
                float u11r = cp * c,  u11i = sp * c;

                const int m = 8 >> q;
#pragma unroll
                for (int i0 = 0; i0 < DIM; ++i0) {
                    if (i0 & m) continue;
                    int i1 = i0 | m;
                    float ar = sr[i0], ai = si[i0];
                    float br = sr[i1], bi = si[i1];
                    sr[i0] = u00r * ar - u00i * ai + u01r * br - u01i * bi;
                    si[i0] = u00r * ai + u00i * ar + u01r * bi + u01i * br;
                    sr[i1] = u10r * ar - u10i * ai + u11r * br - u11i * bi;
                    si[i1] = u10r * ai + u10i * ar + u11r * bi + u11i * br;
                }
            }
            const int rr = (l % (WIRES - 1)) + 1;
#pragma unroll
            for (int i = 0; i < WIRES; ++i) {
                const int mc = 8 >> i;
                const int mt = 8 >> ((i + rr) & (WIRES - 1));
#pragma unroll
                for (int i0 = 0; i0 < DIM; ++i0) {
                    if (!(i0 & mc)) continue;
                    if (i0 & mt) continue;
                    int i1 = i0 | mt;
                    float tr = sr[i0], ti = si[i0];
                    sr[i0] = sr[i1]; si[i0] = si[i1];
                    sr[i1] = tr;     si[i1] = ti;
                }
            }
        }

        if (tid < DIM) {
#pragma unroll
            for (int row = 0; row < DIM; ++row) {
                Utr[row][tid] = sr[row];
                Uti[row][tid] = si[row];
            }
        }
    }
    __syncthreads();

    if (tid < DIM) {
        int k = tid;
        float accR = 0.f, accI = 0.f;
#pragma unroll
        for (int j = 0; j < 9; ++j) {
            recs[k * 32 + j]      = Utr[k][j];
            recs[k * 32 + 16 + j] = Uti[k][j];
        }
#pragma unroll
        for (int j = 9; j < DIM; ++j) {
            accR += Utr[k][j];
            accI += Uti[k][j];
        }
        recs[k * 32 + 9]  = 0.01f * accR;
        recs[k * 32 + 25] = 0.01f * accI;
    }
    __syncthreads();

    // ---- 3) evaluate 4 pixels x 16 channels ----
    float scale[4];
#pragma unroll
    for (int i = 0; i < 4; ++i) {
        float n2 = 7.0f * 1e-4f;    // 7 tail entries of 0.01^2
#pragma unroll
        for (int dy = 0; dy < 3; ++dy)
#pragma unroll
            for (int dj = 0; dj < 3; ++dj) {
                float pv = r[dy][i + dj];
                n2 = fmaf(pv, pv, n2);
            }
        scale[i] = 8.0f / n2;       // (DIM*0.5)/||p||^2
    }

    float* o = out + ((size_t)b * OUT_C) * (H * W) + yc * W + xg;

#pragma unroll
    for (int k = 0; k < OUT_C; ++k) {
        const float* rec = &recs[k * 32];           // 128B-aligned
        f32x4 ra0 = *(const f32x4*)(rec);           // Ur[0..3]
        f32x4 ra1 = *(const f32x4*)(rec + 4);       // Ur[4..7]
        float r8  = rec[8];
        float dR  = rec[9];
        f32x4 ia0 = *(const f32x4*)(rec + 16);      // Ui[0..3]
        f32x4 ia1 = *(const f32x4*)(rec + 20);      // Ui[4..7]
        float i8  = rec[24];
        float dI  = rec[25];

        f32x4 res;
#pragma unroll
        for (int i = 0; i < 4; ++i) {
            float u = dR;
            float v = dI;
#pragma unroll
            for (int j = 0; j < 9; ++j) {
                float cR = (j < 4) ? ra0[j & 3] : ((j < 8) ? ra1[j & 3] : r8);
                float cI = (j < 4) ? ia0[j & 3] : ((j < 8) ? ia1[j & 3] : i8);
                float pv = r[j / 3][i + (j % 3)];
                u = fmaf(cR, pv, u);
                v = fmaf(cI, pv, v);
            }
            float val = fmaf(u, u, v * v) * scale[i];
            res[i] = fminf(val, 1.0f);
        }
        *(f32x4*)(o + (size_t)k * (H * W)) = res;   // 16B-aligned (xg%4==0)
    }
}

extern "C" void kernel_launch(void* const* d_in, const int* in_sizes, int n_in,
                              void* d_out, int out_size, void* d_ws, size_t ws_size,
                              hipStream_t stream) {
    const float* x = (const float*)d_in[0];        // [16,1,128,128] f32
    const float* w = (const float*)d_in[1];        // [2,4,3] f32
    float* out = (float*)d_out;                    // [16,16,128,128] f32

    // 256 blocks x 256 threads x 4 px = 262144 pixels, single dispatch
    qconv_fused<<<256, 256, 0, stream>>>(x, w, out);
}